// Round 1
// 379.558 us; speedup vs baseline: 1.0312x; 1.0312x over previous
//
#include <hip/hip_runtime.h>

#define B 32
#define LC 512
#define LQ 64
#define DD 1024

// ws layout (floats):
// mfull [B*LC]              @ 0       (16384 floats)
// q2c   [B*DD]              @ 16384   (32768 floats)
// P     [B*LC*LQ] bf16      @ 49152   (524288 floats as 1M shorts)

typedef __attribute__((ext_vector_type(8))) short bf16x8;   // 8 bf16 (4 VGPRs)
typedef __attribute__((ext_vector_type(4))) float f32x4;    // MFMA C/D

__device__ inline short f2bf(float f) {
    unsigned u = __builtin_bit_cast(unsigned, f);
    u += 0x7FFFu + ((u >> 16) & 1u);   // RNE
    return (short)(u >> 16);
}

__device__ inline bf16x8 pack8(float4 a, float4 b) {
    bf16x8 r;
    r[0] = f2bf(a.x); r[1] = f2bf(a.y); r[2] = f2bf(a.z); r[3] = f2bf(a.w);
    r[4] = f2bf(b.x); r[5] = f2bf(b.y); r[6] = f2bf(b.z); r[7] = f2bf(b.w);
    return r;
}

__device__ inline float dot4(float4 a, float4 b) {
    return a.x * b.x + a.y * b.y + a.z * b.z + a.w * b.w;
}

// ---------------- kernel 1: sim tile via bf16 MFMA, fused s1 + s0 + row softmax ----------------
// 512 blocks (2/CU), 256 threads = 4 waves. Block tile: M=32 rows x N=64 cols (full Lq).
// Wave w handles n-tile w*16..+15, both m-tiles. K chunks of 64.
// Outputs: P[b,i,j] = softmax_j(sim) in bf16; mfull[b,i] = max_j sim.
__global__ __launch_bounds__(256) void k1_sim(const float* __restrict__ c,
                                              const float* __restrict__ q,
                                              const float* __restrict__ proj_c,
                                              const float* __restrict__ proj_q,
                                              const float* __restrict__ proj_cq,
                                              short* __restrict__ P,
                                              float* __restrict__ mfull) {
    const int b  = blockIdx.x >> 4;
    const int i0 = (blockIdx.x & 15) * 32;
    const int t  = threadIdx.x;
    const int w  = t >> 6, lane = t & 63;
    const int l15 = lane & 15, quad = lane >> 4;

    __shared__ __align__(16) short sA[32][72];   // [row i][k], pad 72 (2-way on frag reads)
    __shared__ __align__(16) short sB[64][72];   // [row j][k]
    __shared__ float rmaxL[32][4];
    __shared__ float rsumL[32][4];
    __shared__ float s0red[32][8];
    __shared__ float s1red[64][4];
    __shared__ float s1L[64];

    const int arow = t >> 3, ag = t & 7;    // A stage: row, d-off ag*8 (8 floats/thread)
    const int brow = t >> 2, bg = t & 3;    // B stage: row, d-off bg*16 (16 floats/thread)

    const float* cbase = c + (size_t)(b * LC + i0 + arow) * DD + ag * 8;
    const float* qbase = q + (size_t)(b * LQ + brow) * DD + bg * 16;

    f32x4 acc[2] = {{0.f,0.f,0.f,0.f},{0.f,0.f,0.f,0.f}};
    float s0p = 0.f, s1p = 0.f;

    // prefetch chunk 0
    float4 a0 = *(const float4*)(cbase + 0);
    float4 a1 = *(const float4*)(cbase + 4);
    float4 b0 = *(const float4*)(qbase + 0);
    float4 b1 = *(const float4*)(qbase + 4);
    float4 b2 = *(const float4*)(qbase + 8);
    float4 b3 = *(const float4*)(qbase + 12);

    for (int kc = 0; kc < 16; ++kc) {
        float4 na0, na1, nb0, nb1, nb2, nb3;
        if (kc < 15) {
            const float* cn = cbase + (kc + 1) * 64;
            const float* qn = qbase + (kc + 1) * 64;
            na0 = *(const float4*)(cn + 0);
            na1 = *(const float4*)(cn + 4);
            nb0 = *(const float4*)(qn + 0);
            nb1 = *(const float4*)(qn + 4);
            nb2 = *(const float4*)(qn + 8);
            nb3 = *(const float4*)(qn + 12);
        }
        // convert + stage + s0/s1 partial dots (proj vectors are L1-hot, 4 KB each)
        {
            const float* pcq = proj_cq + kc * 64 + ag * 8;
            const float* pc  = proj_c  + kc * 64 + ag * 8;
            const float* pq  = proj_q  + kc * 64 + bg * 16;
            float4 p0 = *(const float4*)(pcq + 0);
            float4 p1 = *(const float4*)(pcq + 4);
            float4 c0 = *(const float4*)(pc + 0);
            float4 c1 = *(const float4*)(pc + 4);
            float4 pq0 = *(const float4*)(pq + 0);
            float4 pq1 = *(const float4*)(pq + 4);
            float4 pq2 = *(const float4*)(pq + 8);
            float4 pq3 = *(const float4*)(pq + 12);
            s0p += dot4(a0, c0) + dot4(a1, c1);
            s1p += dot4(b0, pq0) + dot4(b1, pq1) + dot4(b2, pq2) + dot4(b3, pq3);
            float4 m0 = {a0.x * p0.x, a0.y * p0.y, a0.z * p0.z, a0.w * p0.w};
            float4 m1 = {a1.x * p1.x, a1.y * p1.y, a1.z * p1.z, a1.w * p1.w};
            *(bf16x8*)&sA[arow][ag * 8] = pack8(m0, m1);
            *(bf16x8*)&sB[brow][bg * 16 + 0] = pack8(b0, b1);
            *(bf16x8*)&sB[brow][bg * 16 + 8] = pack8(b2, b3);
        }
        __syncthreads();
        // MFMA: 2 k-steps x (1 B-frag + 2 A-frags, 2 mfma)
#pragma unroll
        for (int s = 0; s < 2; ++s) {
            int ko = s * 32 + quad * 8;
            bf16x8 bf = *(const bf16x8*)&sB[w * 16 + l15][ko];
#pragma unroll
            for (int mt = 0; mt < 2; ++mt) {
                bf16x8 af = *(const bf16x8*)&sA[mt * 16 + l15][ko];
                acc[mt] = __builtin_amdgcn_mfma_f32_16x16x32_bf16(af, bf, acc[mt], 0, 0, 0);
            }
        }
        __syncthreads();
        if (kc < 15) { a0 = na0; a1 = na1; b0 = nb0; b1 = nb1; b2 = nb2; b3 = nb3; }
    }

    // ---- epilogue: reduce s1 across bg, add to acc, row softmax, write P bf16 + mfull ----
    s0red[arow][ag] = s0p;
    s1red[brow][bg] = s1p;
    __syncthreads();
    if (t < 64) s1L[t] = s1red[t][0] + s1red[t][1] + s1red[t][2] + s1red[t][3];
    __syncthreads();

    const float s1j = s1L[w * 16 + l15];
    float v[2][4];
#pragma unroll
    for (int mt = 0; mt < 2; ++mt) {
#pragma unroll
        for (int r = 0; r < 4; ++r) {
            float vv = acc[mt][r] + s1j;
            v[mt][r] = vv;
            float rm = vv;
#pragma unroll
            for (int off = 1; off < 16; off <<= 1) rm = fmaxf(rm, __shfl_xor(rm, off, 16));
            if (l15 == 0) rmaxL[mt * 16 + quad * 4 + r][w] = rm;
        }
    }
    __syncthreads();
    float e[2][4];
#pragma unroll
    for (int mt = 0; mt < 2; ++mt) {
#pragma unroll
        for (int r = 0; r < 4; ++r) {
            int row = mt * 16 + quad * 4 + r;
            float m = fmaxf(fmaxf(rmaxL[row][0], rmaxL[row][1]),
                            fmaxf(rmaxL[row][2], rmaxL[row][3]));
            float ee = __expf(v[mt][r] - m);
            e[mt][r] = ee;
            float se = ee;
#pragma unroll
            for (int off = 1; off < 16; off <<= 1) se += __shfl_xor(se, off, 16);
            if (l15 == 0) rsumL[row][w] = se;
        }
    }
    __syncthreads();
#pragma unroll
    for (int mt = 0; mt < 2; ++mt) {
#pragma unroll
        for (int r = 0; r < 4; ++r) {
            int row = mt * 16 + quad * 4 + r;
            float s = rsumL[row][0] + rsumL[row][1] + rsumL[row][2] + rsumL[row][3];
            P[(size_t)(b * LC + i0 + row) * LQ + w * 16 + l15] = f2bf(e[mt][r] / s);
        }
    }
    if (t < 32) {
        float s0v = 0.f;
#pragma unroll
        for (int k = 0; k < 8; ++k) s0v += s0red[t][k];
        float mm = fmaxf(fmaxf(rmaxL[t][0], rmaxL[t][1]),
                         fmaxf(rmaxL[t][2], rmaxL[t][3]));
        mfull[b * LC + i0 + t] = mm + s0v;
    }
}

// ---------------- kernel 2: fused softmax_i(mfull) + q2c[b,d] = sum_i a[i]*c[b,i,d] ----------------
// 256 blocks (b*8 + d-slice). Softmax over mfull[b,:] recomputed per block (2 KB, L2-hot).
__global__ __launch_bounds__(256) void k2_q2c(const float* __restrict__ c,
                                              const float* __restrict__ mfull,
                                              float* __restrict__ q2c) {
    const int b  = blockIdx.x >> 3;
    const int d0 = (blockIdx.x & 7) * 128;
    const int t  = threadIdx.x;
    __shared__ float aL[LC];
    __shared__ float redm[4];
    __shared__ float reds[4];

    float m0 = mfull[b * LC + t];
    float m1 = mfull[b * LC + 256 + t];
    float mx = fmaxf(m0, m1);
#pragma unroll
    for (int off = 32; off; off >>= 1) mx = fmaxf(mx, __shfl_xor(mx, off, 64));
    if ((t & 63) == 0) redm[t >> 6] = mx;
    __syncthreads();
    float bm = fmaxf(fmaxf(redm[0], redm[1]), fmaxf(redm[2], redm[3]));
    float e0 = __expf(m0 - bm), e1 = __expf(m1 - bm);
    float s = e0 + e1;
#pragma unroll
    for (int off = 32; off; off >>= 1) s += __shfl_xor(s, off, 64);
    if ((t & 63) == 0) reds[t >> 6] = s;
    __syncthreads();
    float bs = reds[0] + reds[1] + reds[2] + reds[3];
    float inv = 1.0f / bs;
    aL[t] = e0 * inv;
    aL[t + 256] = e1 * inv;
    __syncthreads();

    const int tx = t & 31, ty = t >> 5;
    float4 acc = {0.f, 0.f, 0.f, 0.f};
    const float* cb = c + (size_t)b * LC * DD + d0 + tx * 4;
    for (int i = ty; i < LC; i += 8) {
        float a = aL[i];
        float4 cv = *(const float4*)(cb + (size_t)i * DD);
        acc.x += a * cv.x; acc.y += a * cv.y; acc.z += a * cv.z; acc.w += a * cv.w;
    }
    __shared__ __align__(16) float4 red[8][32];
    red[ty][tx] = acc;
    __syncthreads();
    if (t < 32) {
        float4 sv = red[0][t];
#pragma unroll
        for (int k = 1; k < 8; ++k) {
            float4 v2 = red[k][t];
            sv.x += v2.x; sv.y += v2.y; sv.z += v2.z; sv.w += v2.w;
        }
        *(float4*)(q2c + b * DD + d0 + t * 4) = sv;
    }
}

// ---------------- kernel 3: bf16 MFMA c2q from precomputed P -> concat write ----------------
// 1024 blocks (b, i0-tile, D-half), 256 threads = 4 waves, ~4 blocks/CU.
// P fragments loaded once into registers (invariant over d-chunks); no softmax phase.
__global__ __launch_bounds__(256) void k3_out(const float* __restrict__ c,
                                              const float* __restrict__ q,
                                              const short* __restrict__ P,
                                              const float* __restrict__ q2c,
                                              float* __restrict__ out) {
    const int b  = blockIdx.x >> 5;
    const int i0 = ((blockIdx.x >> 1) & 15) * 32;
    const int h  = blockIdx.x & 1;          // D-half: chunks h*8 .. h*8+7
    const int t  = threadIdx.x;
    const int w  = t >> 6, lane = t & 63;
    const int l15 = lane & 15, quad = lane >> 4;

    __shared__ __align__(16) short sBq[64][72];   // q^T per chunk, [d][j]
    __shared__ __align__(16) float ct[32][68];    // c2q transpose buffer [i][d]

    // P A-fragments: paf[s][mt] = P[i0 + mt*16 + l15][s*32 + quad*8 ..+7], bf16, 16B-aligned
    bf16x8 paf[2][2];
#pragma unroll
    for (int s = 0; s < 2; ++s)
#pragma unroll
        for (int mt = 0; mt < 2; ++mt)
            paf[s][mt] = *(const bf16x8*)&P[(size_t)(b * LC + i0 + mt * 16 + l15) * LQ
                                           + s * 32 + quad * 8];

    const int j0 = (t & 31) * 2, dg = t >> 5;     // q staging: 2 j-rows, 8 d each
    const int erow = t >> 4, ed = (t & 15) * 4;   // epilogue: rows erow, erow+16; 4 d

    const int dcb = h * 8;
    const float* qb0 = q + (size_t)(b * LQ + j0) * DD + dg * 8 + dcb * 64;
    const float* qb1 = qb0 + DD;

    // prefetch q chunk 0 of this half
    float4 r0 = *(const float4*)(qb0 + 0);
    float4 r1 = *(const float4*)(qb0 + 4);
    float4 r2 = *(const float4*)(qb1 + 0);
    float4 r3 = *(const float4*)(qb1 + 4);

    for (int dci = 0; dci < 8; ++dci) {
        const int d0 = (dcb + dci) * 64;
        float4 n0, n1, n2, n3;
        if (dci < 7) {
            n0 = *(const float4*)(qb0 + (dci + 1) * 64);
            n1 = *(const float4*)(qb0 + (dci + 1) * 64 + 4);
            n2 = *(const float4*)(qb1 + (dci + 1) * 64);
            n3 = *(const float4*)(qb1 + (dci + 1) * 64 + 4);
        }
        // epilogue global loads for this chunk (latency hidden behind MFMA phase)
        float4 cc0 = *(const float4*)(c + (size_t)(b * LC + i0 + erow) * DD + d0 + ed);
        float4 cc1 = *(const float4*)(c + (size_t)(b * LC + i0 + erow + 16) * DD + d0 + ed);
        float4 g2  = *(const float4*)(q2c + b * DD + d0 + ed);

        // stage q^T as bf16 pairs: sBq[d][j0], low=j0, high=j0+1
        const float* fr0 = (const float*)&r0;
        const float* fr1 = (const float*)&r1;
        const float* fr2 = (const float*)&r2;
        const float* fr3 = (const float*)&r3;
#pragma unroll
        for (int e = 0; e < 8; ++e) {
            float v0 = (e < 4) ? fr0[e] : fr1[e - 4];
            float v1 = (e < 4) ? fr2[e] : fr3[e - 4];
            unsigned pk = (unsigned)(unsigned short)f2bf(v0)
                        | ((unsigned)(unsigned short)f2bf(v1) << 16);
            *(unsigned*)&sBq[dg * 8 + e][j0] = pk;
        }
        __syncthreads();   // B1

        // MFMA: c2q[i][d] = sum_j P[i][j] q[j][d];  K = 64 (2 k-steps), fresh acc
        f32x4 acc2[2] = {{0.f,0.f,0.f,0.f},{0.f,0.f,0.f,0.f}};
#pragma unroll
        for (int s = 0; s < 2; ++s) {
            int ko = s * 32 + quad * 8;
            bf16x8 bf = *(const bf16x8*)&sBq[w * 16 + l15][ko];
#pragma unroll
            for (int mt = 0; mt < 2; ++mt)
                acc2[mt] = __builtin_amdgcn_mfma_f32_16x16x32_bf16(paf[s][mt], bf, acc2[mt], 0, 0, 0);
        }
        // scatter acc -> ct (transpose to row-major for coalesced writes)
#pragma unroll
        for (int mt = 0; mt < 2; ++mt)
#pragma unroll
            for (int r = 0; r < 4; ++r)
                ct[mt * 16 + quad * 4 + r][w * 16 + l15] = acc2[mt][r];
        __syncthreads();   // B2

        // epilogue: 2 rows x 16B, 4 output segments, fully coalesced 256B/row-inst
#pragma unroll
        for (int k = 0; k < 2; ++k) {
            int row = erow + 16 * k;
            float4 cc = k ? cc1 : cc0;
            float4 cqv = *(const float4*)&ct[row][ed];
            float* ob = out + (size_t)(b * LC + i0 + row) * (4 * DD) + d0 + ed;
            *(float4*)(ob) = cc;
            *(float4*)(ob + DD) = cqv;
            float4 o2 = {cc.x * g2.x, cc.y * g2.y, cc.z * g2.z, cc.w * g2.w};
            *(float4*)(ob + 2 * DD) = o2;
            float4 o3 = {cc.x * cqv.x, cc.y * cqv.y, cc.z * cqv.z, cc.w * cqv.w};
            *(float4*)(ob + 3 * DD) = o3;
        }
        // next sBq writes are fenced by B2 of this iteration; ct reads precede next B1.
        if (dci < 7) { r0 = n0; r1 = n1; r2 = n2; r3 = n3; }
    }
}

extern "C" void kernel_launch(void* const* d_in, const int* in_sizes, int n_in,
                              void* d_out, int out_size, void* d_ws, size_t ws_size,
                              hipStream_t stream) {
    const float* c       = (const float*)d_in[0];
    const float* q       = (const float*)d_in[1];
    const float* proj_c  = (const float*)d_in[2];
    const float* proj_q  = (const float*)d_in[3];
    const float* proj_cq = (const float*)d_in[4];
    float* out = (float*)d_out;
    float* ws  = (float*)d_ws;

    float* mfull = ws;                       // [B*LC]
    float* q2c   = ws + 16384;               // [B*DD]
    short* P     = (short*)(ws + 49152);     // [B*LC*LQ] bf16

    hipLaunchKernelGGL(k1_sim, dim3(512),  dim3(256), 0, stream,
                       c, q, proj_c, proj_q, proj_cq, P, mfull);
    hipLaunchKernelGGL(k2_q2c, dim3(256),  dim3(256), 0, stream, c, mfull, q2c);
    hipLaunchKernelGGL(k3_out, dim3(1024), dim3(256), 0, stream, c, q, P, q2c, out);
}